// Round 10
// baseline (152.863 us; speedup 1.0000x reference)
//
#include <hip/hip_runtime.h>

#define S_LEN 1024
#define D_DIM 128
#define KVBLK 32
#define BH_N 128

typedef __attribute__((ext_vector_type(8))) short short8;
typedef __attribute__((ext_vector_type(4))) short short4v;
typedef __attribute__((ext_vector_type(4))) float f32x4;
typedef __attribute__((ext_vector_type(16))) float f32x16;
typedef __attribute__((ext_vector_type(4))) unsigned int uint4v;

__device__ __forceinline__ unsigned short f2bf(float f) {
  union { float f; unsigned u; } x; x.f = f;
  unsigned r = x.u + 0x7fffu + ((x.u >> 16) & 1u);
  return (unsigned short)(r >> 16);
}

__device__ __forceinline__ short8 pack8(float4 a, float4 b) {
  short8 f;
  f[0] = (short)f2bf(a.x); f[1] = (short)f2bf(a.y);
  f[2] = (short)f2bf(a.z); f[3] = (short)f2bf(a.w);
  f[4] = (short)f2bf(b.x); f[5] = (short)f2bf(b.y);
  f[6] = (short)f2bf(b.z); f[7] = (short)f2bf(b.w);
  return f;
}

__device__ __forceinline__ void gload_lds16(const void* g, void* l) {
  __builtin_amdgcn_global_load_lds(
      (const __attribute__((address_space(1))) unsigned int*)g,
      (__attribute__((address_space(3))) unsigned int*)l, 16, 0, 0);
}

// exp2(clamped) -> cvt_pk bf16 -> permlane assemble of the PV A-frag for
// k-chunk c (k = c*16 + 8*hi + 0..7); accumulates this lane's l partial.
__device__ __forceinline__ short8 packP(const f32x16 sacc, const int c, float& l_r) {
  float p0 = exp2f(fminf(sacc[8 * c + 0], 80.f));
  float p1 = exp2f(fminf(sacc[8 * c + 1], 80.f));
  unsigned w0;
  asm("v_cvt_pk_bf16_f32 %0, %1, %2" : "=v"(w0) : "v"(p0), "v"(p1));
  float p2 = exp2f(fminf(sacc[8 * c + 2], 80.f));
  float p3 = exp2f(fminf(sacc[8 * c + 3], 80.f));
  unsigned w1;
  asm("v_cvt_pk_bf16_f32 %0, %1, %2" : "=v"(w1) : "v"(p2), "v"(p3));
  l_r += (p0 + p1) + (p2 + p3);
  float p4 = exp2f(fminf(sacc[8 * c + 4], 80.f));
  float p5 = exp2f(fminf(sacc[8 * c + 5], 80.f));
  unsigned w2;
  asm("v_cvt_pk_bf16_f32 %0, %1, %2" : "=v"(w2) : "v"(p4), "v"(p5));
  float p6 = exp2f(fminf(sacc[8 * c + 6], 80.f));
  float p7 = exp2f(fminf(sacc[8 * c + 7], 80.f));
  unsigned w3;
  asm("v_cvt_pk_bf16_f32 %0, %1, %2" : "=v"(w3) : "v"(p6), "v"(p7));
  l_r += (p4 + p5) + (p6 + p7);
  asm volatile("v_permlane32_swap_b32 %0, %1" : "+v"(w0), "+v"(w2));
  asm volatile("v_permlane32_swap_b32 %0, %1" : "+v"(w1), "+v"(w3));
  uint4v pw;
  pw[0] = w0; pw[1] = w1; pw[2] = w2; pw[3] = w3;
  return __builtin_bit_cast(short8, pw);
}

// ---------- prepass 1: K f32 -> bf16 row-major ----------
__global__ __launch_bounds__(256) void conv_k(const float* __restrict__ in,
                                              unsigned short* __restrict__ out,
                                              int n8) {
  int i = blockIdx.x * 256 + threadIdx.x;
  int stride = gridDim.x * 256;
  for (; i < n8; i += stride) {
    float4 a = ((const float4*)in)[i * 2];
    float4 b = ((const float4*)in)[i * 2 + 1];
    ((short8*)out)[i] = pack8(a, b);
  }
}

// ---------- prepass 2: V f32 [bh][s][d] -> bf16 VT [bh][d][s] ----------
__global__ __launch_bounds__(256) void conv_vt(const float* __restrict__ v,
                                               unsigned short* __restrict__ vt) {
  __shared__ unsigned short tile[64][72];
  int b = blockIdx.x;  // 128 bh * 16 s-tiles * 2 d-tiles = 4096
  int d0 = (b & 1) * 64;
  int s0 = ((b >> 1) & 15) * 64;
  int bh = b >> 5;
  int t = threadIdx.x;
  #pragma unroll
  for (int i = 0; i < 4; ++i) {
    int s = (t >> 4) + i * 16;
    int dl = (t & 15) * 4;
    float4 x = *(const float4*)(v + ((size_t)(bh * S_LEN) + s0 + s) * D_DIM + d0 + dl);
    tile[s][dl + 0] = f2bf(x.x); tile[s][dl + 1] = f2bf(x.y);
    tile[s][dl + 2] = f2bf(x.z); tile[s][dl + 3] = f2bf(x.w);
  }
  __syncthreads();
  #pragma unroll
  for (int i = 0; i < 2; ++i) {
    int j = i * 256 + t;
    int dl = j >> 3, sc = j & 7;
    short8 w;
    #pragma unroll
    for (int q = 0; q < 8; ++q) w[q] = (short)tile[sc * 8 + q][dl];
    *(short8*)(vt + ((size_t)(bh * D_DIM) + d0 + dl) * S_LEN + s0 + sc * 8) = w;
  }
}

// ---------- main attention: 32x32 MFMA, 4 waves x 64 q (2 groups), shared K/V frags ----------
__global__ __launch_bounds__(256, 2) void attn_main(
    const float* __restrict__ qg, const unsigned short* __restrict__ kbf,
    const unsigned short* __restrict__ vtbf, float* __restrict__ og) {
  __shared__ unsigned short K_lds[2][KVBLK * D_DIM];   // 2 x 8 KB
  __shared__ unsigned short VT_lds[2][D_DIM * KVBLK];  // 2 x 8 KB

  const int tid = threadIdx.x;
  const int lane = tid & 63;
  const int wid = tid >> 6;   // 0..3
  const int l31 = lane & 31;
  const int hi = lane >> 5;   // 0/1

  // grid 512: 4 blocks per bh, all on one XCD
  const int bid = blockIdx.x;
  const int bh = (bid & 7) | ((bid >> 5) << 3);
  const int qt = (bid >> 3) & 3;

  const size_t base = (size_t)bh * (S_LEN * D_DIM);
  const int qw = qt * 256 + wid * 64;  // wave owns q rows [qw, qw+64)

  // Q B-frags for both q-groups, scaled by log2e/128
  short8 qfA[8], qfB[8];
  {
    const float s = 0.0078125f * 1.44269504088896f;
    const float* qpA = qg + base + (size_t)(qw + l31) * D_DIM + hi * 8;
    const float* qpB = qpA + 32 * D_DIM;
    #pragma unroll
    for (int c = 0; c < 8; ++c) {
      float4 a = *(const float4*)(qpA + c * 16);
      float4 b = *(const float4*)(qpA + c * 16 + 4);
      a.x *= s; a.y *= s; a.z *= s; a.w *= s;
      b.x *= s; b.y *= s; b.z *= s; b.w *= s;
      qfA[c] = pack8(a, b);
      float4 e = *(const float4*)(qpB + c * 16);
      float4 f = *(const float4*)(qpB + c * 16 + 4);
      e.x *= s; e.y *= s; e.z *= s; e.w *= s;
      f.x *= s; f.y *= s; f.z *= s; f.w *= s;
      qfB[c] = pack8(e, f);
    }
  }

  // Softmax base fixed at 0 (cancels in o/l); clamp 80 guards exp2 overflow.
  float lA = 0.f, lB = 0.f;
  f32x16 oA[4], oB[4];
  #pragma unroll
  for (int dt = 0; dt < 4; ++dt)
    #pragma unroll
    for (int r = 0; r < 16; ++r) { oA[dt][r] = 0.f; oB[dt][r] = 0.f; }

  const char* kbB = (const char*)(kbf + base);                           // K [s][d]
  const char* vtB = (const char*)(vtbf + (size_t)bh * (D_DIM * S_LEN));  // VT [d][s]

  // loop-invariant per-lane byte offsets (as round 9, verified)
  int koffA, koffB, voff;
  {
    int r0 = wid * 8 + (lane >> 4);
    int c = lane & 15;
    koffA = (r0 * D_DIM + ((c ^ (r0 & 7)) * 8)) * 2;
    int r1 = r0 + 4;
    koffB = (r1 * D_DIM + ((c ^ (r1 & 7)) * 8)) * 2;
    int d0 = wid * 32 + (lane >> 2);
    int c2 = lane & 3;
    voff = (d0 * S_LEN + ((c2 ^ (lane >> 4)) * 8)) * 2;
  }
  const int KRB = l31 * 256 + ((hi ^ (l31 & 7)) << 4);
  const int VRB = l31 * 64 + ((hi ^ ((l31 >> 2) & 3)) << 4);

  #define STAGE(buf, tnext)                                                    \
    {                                                                          \
      const char* ks = kbB + (tnext) * (KVBLK * D_DIM * 2);                    \
      gload_lds16(ks + koffA, &K_lds[buf][(wid * 8) * D_DIM]);                 \
      gload_lds16(ks + koffB, &K_lds[buf][(wid * 8 + 4) * D_DIM]);             \
      const char* vs = vtB + (tnext) * (KVBLK * 2);                            \
      gload_lds16(vs + voff, &VT_lds[buf][(wid * 32) * KVBLK]);                \
      gload_lds16(vs + voff + 16 * S_LEN * 2,                                  \
                  &VT_lds[buf][(wid * 32 + 16) * KVBLK]);                      \
    }

  STAGE(0, 0);
  __syncthreads();

  for (int t = 0; t < S_LEN / KVBLK; ++t) {
    const int cur = t & 1;
    if (t + 1 < S_LEN / KVBLK) STAGE(cur ^ 1, t + 1);

    const char* kl = (const char*)&K_lds[cur][0];
    const char* vl = (const char*)&VT_lds[cur][0];

    // ---- swapped QK^T: two independent chains share each kf ----
    f32x16 sA, sB;
    #pragma unroll
    for (int r = 0; r < 16; ++r) { sA[r] = 0.f; sB[r] = 0.f; }

    __builtin_amdgcn_s_setprio(1);
    #pragma unroll
    for (int c = 0; c < 8; ++c) {
      short8 kf = *(const short8*)(kl + (KRB ^ (c << 5)));
      sA = __builtin_amdgcn_mfma_f32_32x32x16_bf16(kf, qfA[c], sA, 0, 0, 0);
      sB = __builtin_amdgcn_mfma_f32_32x32x16_bf16(kf, qfB[c], sB, 0, 0, 0);
    }
    __builtin_amdgcn_s_setprio(0);

    // ---- softmax + pack (independent A/B blocks; compiler interleaves) ----
    short8 paA0 = packP(sA, 0, lA);
    short8 paA1 = packP(sA, 1, lA);
    short8 paB0 = packP(sB, 0, lB);
    short8 paB1 = packP(sB, 1, lB);

    // ---- PV: each vf feeds both q-groups ----
    __builtin_amdgcn_s_setprio(1);
    {
      const int vx0 = VRB;
      #pragma unroll
      for (int dt = 0; dt < 4; ++dt) {
        short8 vf = *(const short8*)(vl + vx0 + dt * 2048);
        oA[dt] = __builtin_amdgcn_mfma_f32_32x32x16_bf16(paA0, vf, oA[dt], 0, 0, 0);
        oB[dt] = __builtin_amdgcn_mfma_f32_32x32x16_bf16(paB0, vf, oB[dt], 0, 0, 0);
      }
      const int vx1 = VRB ^ 32;
      #pragma unroll
      for (int dt = 0; dt < 4; ++dt) {
        short8 vf = *(const short8*)(vl + vx1 + dt * 2048);
        oA[dt] = __builtin_amdgcn_mfma_f32_32x32x16_bf16(paA1, vf, oA[dt], 0, 0, 0);
        oB[dt] = __builtin_amdgcn_mfma_f32_32x32x16_bf16(paB1, vf, oB[dt], 0, 0, 0);
      }
    }
    __builtin_amdgcn_s_setprio(0);
    __syncthreads();
  }

  // ---- deferred l reduction + epilogue (per-row shfl, no arrays) ----
  float lsA = lA + __shfl_xor(lA, 32);
  float liA = 1.0f / lsA;
  float lsB = lB + __shfl_xor(lB, 32);
  float liB = 1.0f / lsB;
  #pragma unroll
  for (int r = 0; r < 16; ++r) {
    int qr = (r & 3) + 8 * (r >> 2) + 4 * hi;
    float lvA = __shfl(liA, qr, 64);
    float lvB = __shfl(liB, qr, 64);
    #pragma unroll
    for (int dt = 0; dt < 4; ++dt) {
      og[base + (size_t)(qw + qr) * D_DIM + dt * 32 + l31] = oA[dt][r] * lvA;
      og[base + (size_t)(qw + 32 + qr) * D_DIM + dt * 32 + l31] = oB[dt][r] * lvB;
    }
  }
}

// ---------- fallback (fused, f32 inputs) if ws too small ----------
__global__ __launch_bounds__(256) void attn_fused(
    const float* __restrict__ qg, const float* __restrict__ kg,
    const float* __restrict__ vg, float* __restrict__ og) {
  __shared__ unsigned short K_lds[64 * D_DIM];
  __shared__ unsigned short VT_lds[D_DIM * 64];
  __shared__ unsigned short P_lds[4][16 * 64];

  const int tid = threadIdx.x;
  const int lane = tid & 63;
  const int wid = tid >> 6;
  const int l15 = lane & 15;
  const int lg = lane >> 4;

  const int bid = blockIdx.x;
  const int bh = (bid & 7) | ((bid >> 7) << 3);
  const int qt = (bid >> 3) & 15;

  const size_t base = (size_t)bh * (S_LEN * D_DIM);
  const int qw = qt * 64 + wid * 16;

  short8 qf[4];
  {
    const float* qp = qg + base + (size_t)(qw + l15) * D_DIM + lg * 8;
    #pragma unroll
    for (int c = 0; c < 4; ++c) {
      float4 a = *(const float4*)(qp + c * 32);
      float4 b = *(const float4*)(qp + c * 32 + 4);
      const float s = 0.0078125f;
      a.x *= s; a.y *= s; a.z *= s; a.w *= s;
      b.x *= s; b.y *= s; b.z *= s; b.w *= s;
      qf[c] = pack8(a, b);
    }
  }

  float m_r[4], l_r[4];
  f32x4 o_acc[8];
  #pragma unroll
  for (int r = 0; r < 4; ++r) { m_r[r] = -INFINITY; l_r[r] = 0.f; }
  #pragma unroll
  for (int dt = 0; dt < 8; ++dt) o_acc[dt] = (f32x4){0.f, 0.f, 0.f, 0.f};

  for (int kv0 = 0; kv0 < S_LEN; kv0 += 64) {
    {
      const float* kb = kg + base + (size_t)kv0 * D_DIM;
      #pragma unroll
      for (int c = tid; c < 64 * D_DIM / 8; c += 256) {
        int row = c >> 4, dc = c & 15;
        const float* p = kb + row * D_DIM + dc * 8;
        float4 a = *(const float4*)p;
        float4 b = *(const float4*)(p + 4);
        int sidx = row * 128 + ((dc * 8) ^ ((row & 7) << 3));
        *(short8*)&K_lds[sidx] = pack8(a, b);
      }
    }
    {
      const float* vb = vg + base + (size_t)kv0 * D_DIM;
      #pragma unroll
      for (int u = tid; u < (64 / 4) * (D_DIM / 4); u += 256) {
        int ib = u & 15;
        int db = u >> 4;
        const float* p = vb + (ib * 4) * D_DIM + db * 4;
        float rr[4][4];
        #pragma unroll
        for (int c = 0; c < 4; ++c) {
          float4 t = *(const float4*)(p + c * D_DIM);
          rr[c][0] = t.x; rr[c][1] = t.y; rr[c][2] = t.z; rr[c][3] = t.w;
        }
        #pragma unroll
        for (int j = 0; j < 4; ++j) {
          short4v w;
          w[0] = (short)f2bf(rr[0][j]); w[1] = (short)f2bf(rr[1][j]);
          w[2] = (short)f2bf(rr[2][j]); w[3] = (short)f2bf(rr[3][j]);
          int row = db * 4 + j;
          int sidx = row * 64 + ((ib * 4) ^ ((row & 7) << 3));
          *(short4v*)&VT_lds[sidx] = w;
        }
      }
    }
    __syncthreads();

    f32x4 sacc[4];
    #pragma unroll
    for (int tc = 0; tc < 4; ++tc) sacc[tc] = (f32x4){0.f, 0.f, 0.f, 0.f};
    #pragma unroll
    for (int tc = 0; tc < 4; ++tc) {
      int row = tc * 16 + l15;
      #pragma unroll
      for (int ck = 0; ck < 4; ++ck) {
        int sidx = row * 128 + ((ck * 32 + lg * 8) ^ ((row & 7) << 3));
        short8 kf = *(const short8*)&K_lds[sidx];
        sacc[tc] = __builtin_amdgcn_mfma_f32_16x16x32_bf16(qf[ck], kf, sacc[tc], 0, 0, 0);
      }
    }

    float alpha[4], ps[4];
    #pragma unroll
    for (int r = 0; r < 4; ++r) {
      float a = fmaxf(fmaxf(sacc[0][r], sacc[1][r]), fmaxf(sacc[2][r], sacc[3][r]));
      a = fmaxf(a, __shfl_xor(a, 1));
      a = fmaxf(a, __shfl_xor(a, 2));
      a = fmaxf(a, __shfl_xor(a, 4));
      a = fmaxf(a, __shfl_xor(a, 8));
      float mn = fmaxf(m_r[r], a);
      alpha[r] = __expf(m_r[r] - mn);
      m_r[r] = mn;
      ps[r] = 0.f;
    }
    #pragma unroll
    for (int tc = 0; tc < 4; ++tc) {
      #pragma unroll
      for (int r = 0; r < 4; ++r) {
        float p = __expf(sacc[tc][r] - m_r[r]);
        ps[r] += p;
        int prow = lg * 4 + r;
        int pcol = tc * 16 + l15;
        P_lds[wid][prow * 64 + (pcol ^ ((prow & 7) << 3))] = f2bf(p);
      }
    }
    #pragma unroll
    for (int r = 0; r < 4; ++r) {
      float s = ps[r];
      s += __shfl_xor(s, 1); s += __shfl_xor(s, 2);
      s += __shfl_xor(s, 4); s += __shfl_xor(s, 8);
      l_r[r] = l_r[r] * alpha[r] + s;
    }
    #pragma unroll
    for (int dt = 0; dt < 8; ++dt) {
      #pragma unroll
      for (int r = 0; r < 4; ++r) o_acc[dt][r] *= alpha[r];
    }

    #pragma unroll
    for (int kc = 0; kc < 2; ++kc) {
      int pidx = l15 * 64 + ((kc * 32 + lg * 8) ^ ((l15 & 7) << 3));
      short8 pf = *(const short8*)&P_lds[wid][pidx];
      #pragma unroll
      for (int dt = 0; dt < 8; ++dt) {
        int vrow = dt * 16 + l15;
        int vidx = vrow * 64 + ((kc * 32 + lg * 8) ^ ((vrow & 7) << 3));
        short8 vf = *(const short8*)&VT_lds[vidx];
        o_acc[dt] = __builtin_amdgcn_mfma_f32_16x16x32_bf16(pf, vf, o_acc[dt], 0, 0, 0);
      }
    }
    __syncthreads();
  }

  #pragma unroll
  for (int r = 0; r < 4; ++r) {
    float inv = 1.0f / l_r[r];
    float* op = og + base + (size_t)(qw + lg * 4 + r) * D_DIM + l15;
    #pragma unroll
    for (int dt = 0; dt < 8; ++dt) op[dt * 16] = o_acc[dt][r] * inv;
  }
}

extern "C" void kernel_launch(void* const* d_in, const int* in_sizes, int n_in,
                              void* d_out, int out_size, void* d_ws, size_t ws_size,
                              hipStream_t stream) {
  const float* q = (const float*)d_in[0];
  const float* k = (const float*)d_in[1];
  const float* v = (const float*)d_in[2];
  float* o = (float*)d_out;

  const size_t n_elem = (size_t)BH_N * S_LEN * D_DIM;
  const size_t need = 2 * n_elem * sizeof(unsigned short);

  if (ws_size >= need) {
    unsigned short* kbf = (unsigned short*)d_ws;
    unsigned short* vtbf = kbf + n_elem;
    conv_k<<<dim3(2048), dim3(256), 0, stream>>>(k, kbf, (int)(n_elem / 8));
    conv_vt<<<dim3(4096), dim3(256), 0, stream>>>(v, vtbf);
    attn_main<<<dim3(512), dim3(256), 0, stream>>>(q, kbf, vtbf, o);
  } else {
    attn_fused<<<dim3(2048), dim3(256), 0, stream>>>(q, k, v, o);
  }
}

// Round 11
// 139.294 us; speedup vs baseline: 1.0974x; 1.0974x over previous
//
#include <hip/hip_runtime.h>

#define S_LEN 1024
#define D_DIM 128
#define KVBLK 32
#define NT (S_LEN / KVBLK)
#define BH_N 128

typedef __attribute__((ext_vector_type(8))) short short8;
typedef __attribute__((ext_vector_type(4))) short short4v;
typedef __attribute__((ext_vector_type(4))) float f32x4;
typedef __attribute__((ext_vector_type(16))) float f32x16;
typedef __attribute__((ext_vector_type(4))) unsigned int uint4v;

__device__ __forceinline__ unsigned short f2bf(float f) {
  union { float f; unsigned u; } x; x.f = f;
  unsigned r = x.u + 0x7fffu + ((x.u >> 16) & 1u);
  return (unsigned short)(r >> 16);
}

__device__ __forceinline__ short8 pack8(float4 a, float4 b) {
  short8 f;
  f[0] = (short)f2bf(a.x); f[1] = (short)f2bf(a.y);
  f[2] = (short)f2bf(a.z); f[3] = (short)f2bf(a.w);
  f[4] = (short)f2bf(b.x); f[5] = (short)f2bf(b.y);
  f[6] = (short)f2bf(b.z); f[7] = (short)f2bf(b.w);
  return f;
}

__device__ __forceinline__ void gload_lds16(const void* g, void* l) {
  __builtin_amdgcn_global_load_lds(
      (const __attribute__((address_space(1))) unsigned int*)g,
      (__attribute__((address_space(3))) unsigned int*)l, 16, 0, 0);
}

// exp2(clamped) -> cvt_pk bf16 -> permlane assemble of the PV A-frag for
// k-chunk c (k = c*16 + 8*hi + 0..7); accumulates this lane's l partial.
__device__ __forceinline__ short8 packP(const f32x16 sacc, const int c, float& l_r) {
  float p0 = exp2f(fminf(sacc[8 * c + 0], 80.f));
  float p1 = exp2f(fminf(sacc[8 * c + 1], 80.f));
  unsigned w0;
  asm("v_cvt_pk_bf16_f32 %0, %1, %2" : "=v"(w0) : "v"(p0), "v"(p1));
  float p2 = exp2f(fminf(sacc[8 * c + 2], 80.f));
  float p3 = exp2f(fminf(sacc[8 * c + 3], 80.f));
  unsigned w1;
  asm("v_cvt_pk_bf16_f32 %0, %1, %2" : "=v"(w1) : "v"(p2), "v"(p3));
  l_r += (p0 + p1) + (p2 + p3);
  float p4 = exp2f(fminf(sacc[8 * c + 4], 80.f));
  float p5 = exp2f(fminf(sacc[8 * c + 5], 80.f));
  unsigned w2;
  asm("v_cvt_pk_bf16_f32 %0, %1, %2" : "=v"(w2) : "v"(p4), "v"(p5));
  float p6 = exp2f(fminf(sacc[8 * c + 6], 80.f));
  float p7 = exp2f(fminf(sacc[8 * c + 7], 80.f));
  unsigned w3;
  asm("v_cvt_pk_bf16_f32 %0, %1, %2" : "=v"(w3) : "v"(p6), "v"(p7));
  l_r += (p4 + p5) + (p6 + p7);
  asm volatile("v_permlane32_swap_b32 %0, %1" : "+v"(w0), "+v"(w2));
  asm volatile("v_permlane32_swap_b32 %0, %1" : "+v"(w1), "+v"(w3));
  uint4v pw;
  pw[0] = w0; pw[1] = w1; pw[2] = w2; pw[3] = w3;
  return __builtin_bit_cast(short8, pw);
}

// ---------- prepass 1: K f32 -> bf16 row-major ----------
__global__ __launch_bounds__(256) void conv_k(const float* __restrict__ in,
                                              unsigned short* __restrict__ out,
                                              int n8) {
  int i = blockIdx.x * 256 + threadIdx.x;
  int stride = gridDim.x * 256;
  for (; i < n8; i += stride) {
    float4 a = ((const float4*)in)[i * 2];
    float4 b = ((const float4*)in)[i * 2 + 1];
    ((short8*)out)[i] = pack8(a, b);
  }
}

// ---------- prepass 2: V f32 [bh][s][d] -> bf16 VT [bh][d][s] ----------
__global__ __launch_bounds__(256) void conv_vt(const float* __restrict__ v,
                                               unsigned short* __restrict__ vt) {
  __shared__ unsigned short tile[64][72];
  int b = blockIdx.x;  // 128 bh * 16 s-tiles * 2 d-tiles = 4096
  int d0 = (b & 1) * 64;
  int s0 = ((b >> 1) & 15) * 64;
  int bh = b >> 5;
  int t = threadIdx.x;
  #pragma unroll
  for (int i = 0; i < 4; ++i) {
    int s = (t >> 4) + i * 16;
    int dl = (t & 15) * 4;
    float4 x = *(const float4*)(v + ((size_t)(bh * S_LEN) + s0 + s) * D_DIM + d0 + dl);
    tile[s][dl + 0] = f2bf(x.x); tile[s][dl + 1] = f2bf(x.y);
    tile[s][dl + 2] = f2bf(x.z); tile[s][dl + 3] = f2bf(x.w);
  }
  __syncthreads();
  #pragma unroll
  for (int i = 0; i < 2; ++i) {
    int j = i * 256 + t;
    int dl = j >> 3, sc = j & 7;
    short8 w;
    #pragma unroll
    for (int q = 0; q < 8; ++q) w[q] = (short)tile[sc * 8 + q][dl];
    *(short8*)(vt + ((size_t)(bh * D_DIM) + d0 + dl) * S_LEN + s0 + sc * 8) = w;
  }
}

// ---------- main attention: 32x32 MFMA, pipelined softmax(t) || QKT(t+1) || PV(t) ----------
__global__ __launch_bounds__(256, 3) void attn_main(
    const float* __restrict__ qg, const unsigned short* __restrict__ kbf,
    const unsigned short* __restrict__ vtbf, float* __restrict__ og) {
  __shared__ unsigned short K_lds[3][KVBLK * D_DIM];   // 3-slot ring, 24 KB
  __shared__ unsigned short VT_lds[3][D_DIM * KVBLK];  // 3-slot ring, 24 KB

  const int tid = threadIdx.x;
  const int lane = tid & 63;
  const int wid = tid >> 6;   // 0..3
  const int l31 = lane & 31;
  const int hi = lane >> 5;   // 0/1

  const int bid = blockIdx.x;
  const int bh = (bid & 7) | ((bid >> 6) << 3);
  const int qt = (bid >> 3) & 7;

  const size_t base = (size_t)bh * (S_LEN * D_DIM);
  const int qw = qt * 128 + wid * 32;  // wave's 32 q rows

  // Q B-frags, scaled by log2e/128
  short8 qf[8];
  {
    const float* qp = qg + base + (size_t)(qw + l31) * D_DIM + hi * 8;
    const float s = 0.0078125f * 1.44269504088896f;
    #pragma unroll
    for (int c = 0; c < 8; ++c) {
      float4 a = *(const float4*)(qp + c * 16);
      float4 b = *(const float4*)(qp + c * 16 + 4);
      a.x *= s; a.y *= s; a.z *= s; a.w *= s;
      b.x *= s; b.y *= s; b.z *= s; b.w *= s;
      qf[c] = pack8(a, b);
    }
  }

  float l_r = 0.f;
  f32x16 o_acc[4];
  #pragma unroll
  for (int dt = 0; dt < 4; ++dt)
    #pragma unroll
    for (int r = 0; r < 16; ++r) o_acc[dt][r] = 0.f;

  const char* kbB = (const char*)(kbf + base);
  const char* vtB = (const char*)(vtbf + (size_t)bh * (D_DIM * S_LEN));

  // loop-invariant per-lane byte offsets (verified r9)
  int koffA, koffB, voff;
  {
    int r0 = wid * 8 + (lane >> 4);
    int c = lane & 15;
    koffA = (r0 * D_DIM + ((c ^ (r0 & 7)) * 8)) * 2;
    int r1 = r0 + 4;
    koffB = (r1 * D_DIM + ((c ^ (r1 & 7)) * 8)) * 2;
    int d0 = wid * 32 + (lane >> 2);
    int c2 = lane & 3;
    voff = (d0 * S_LEN + ((c2 ^ (lane >> 4)) * 8)) * 2;
  }
  const int KRB = l31 * 256 + ((hi ^ (l31 & 7)) << 4);
  const int VRB = l31 * 64 + ((hi ^ ((l31 >> 2) & 3)) << 4);

  #define STAGE(slot, tnext)                                                   \
    {                                                                          \
      const char* ks = kbB + (tnext) * (KVBLK * D_DIM * 2);                    \
      gload_lds16(ks + koffA, &K_lds[slot][(wid * 8) * D_DIM]);                \
      gload_lds16(ks + koffB, &K_lds[slot][(wid * 8 + 4) * D_DIM]);            \
      const char* vs = vtB + (tnext) * (KVBLK * 2);                            \
      gload_lds16(vs + voff, &VT_lds[slot][(wid * 32) * KVBLK]);               \
      gload_lds16(vs + voff + 16 * S_LEN * 2,                                  \
                  &VT_lds[slot][(wid * 32 + 16) * KVBLK]);                     \
    }

  // QK^T of one tile (slot) -> lane-local scores S[kv][q=l31]
  #define QKT(slot, dst)                                                       \
    {                                                                          \
      const char* kl = (const char*)&K_lds[slot][0];                           \
      f32x16 s_;                                                               \
      _Pragma("unroll")                                                        \
      for (int r = 0; r < 16; ++r) s_[r] = 0.f;                                \
      _Pragma("unroll")                                                        \
      for (int c = 0; c < 8; ++c) {                                            \
        short8 kf = *(const short8*)(kl + (KRB ^ (c << 5)));                   \
        s_ = __builtin_amdgcn_mfma_f32_32x32x16_bf16(kf, qf[c], s_, 0, 0, 0);  \
      }                                                                        \
      dst = s_;                                                                \
    }

  #define PV(slot, pa0, pa1)                                                   \
    {                                                                          \
      const char* vl = (const char*)&VT_lds[slot][0];                          \
      _Pragma("unroll")                                                        \
      for (int dt = 0; dt < 4; ++dt) {                                         \
        short8 vf = *(const short8*)(vl + (VRB) + dt * 2048);                  \
        o_acc[dt] = __builtin_amdgcn_mfma_f32_32x32x16_bf16(pa0, vf, o_acc[dt], 0, 0, 0); \
      }                                                                        \
      _Pragma("unroll")                                                        \
      for (int dt = 0; dt < 4; ++dt) {                                         \
        short8 vf = *(const short8*)(vl + (VRB ^ 32) + dt * 2048);             \
        o_acc[dt] = __builtin_amdgcn_mfma_f32_32x32x16_bf16(pa1, vf, o_acc[dt], 0, 0, 0); \
      }                                                                        \
    }

  // prologue: stage tiles 0,1; compute QKT(0)
  STAGE(0, 0);
  STAGE(1, 1);
  __syncthreads();

  f32x16 sacc;
  QKT(0, sacc);

  // main pipelined loop: iter t does softmax(t) || QKT(t+1) || PV(t), stages t+2
  int sl = 0;
  for (int t = 0; t < NT - 2; ++t) {
    int slN = sl + 1; if (slN == 3) slN = 0;
    int slNN = slN + 1; if (slNN == 3) slNN = 0;
    STAGE(slNN, t + 2);
    short8 pa0 = packP(sacc, 0, l_r);
    short8 pa1 = packP(sacc, 1, l_r);
    QKT(slN, sacc);
    PV(sl, pa0, pa1);
    __syncthreads();
    sl = slN;
  }
  // tail t = NT-2: no stage; softmax || QKT(NT-1) || PV(NT-2)
  {
    int slN = sl + 1; if (slN == 3) slN = 0;
    short8 pa0 = packP(sacc, 0, l_r);
    short8 pa1 = packP(sacc, 1, l_r);
    QKT(slN, sacc);
    PV(sl, pa0, pa1);
    __syncthreads();
    sl = slN;
  }
  // tail t = NT-1: softmax + PV only
  {
    short8 pa0 = packP(sacc, 0, l_r);
    short8 pa1 = packP(sacc, 1, l_r);
    PV(sl, pa0, pa1);
  }

  // ---- deferred l reduction + epilogue (per-row shfl, no arrays) ----
  float lsum = l_r + __shfl_xor(l_r, 32);  // full denom for q = l31
  float linv = 1.0f / lsum;
  #pragma unroll
  for (int r = 0; r < 16; ++r) {
    int qr = (r & 3) + 8 * (r >> 2) + 4 * hi;
    float lv = __shfl(linv, qr, 64);
    #pragma unroll
    for (int dt = 0; dt < 4; ++dt) {
      og[base + (size_t)(qw + qr) * D_DIM + dt * 32 + l31] = o_acc[dt][r] * lv;
    }
  }
}

// ---------- fallback (fused, f32 inputs) if ws too small ----------
__global__ __launch_bounds__(256) void attn_fused(
    const float* __restrict__ qg, const float* __restrict__ kg,
    const float* __restrict__ vg, float* __restrict__ og) {
  __shared__ unsigned short K_lds[64 * D_DIM];
  __shared__ unsigned short VT_lds[D_DIM * 64];
  __shared__ unsigned short P_lds[4][16 * 64];

  const int tid = threadIdx.x;
  const int lane = tid & 63;
  const int wid = tid >> 6;
  const int l15 = lane & 15;
  const int lg = lane >> 4;

  const int bid = blockIdx.x;
  const int bh = (bid & 7) | ((bid >> 7) << 3);
  const int qt = (bid >> 3) & 15;

  const size_t base = (size_t)bh * (S_LEN * D_DIM);
  const int qw = qt * 64 + wid * 16;

  short8 qf[4];
  {
    const float* qp = qg + base + (size_t)(qw + l15) * D_DIM + lg * 8;
    #pragma unroll
    for (int c = 0; c < 4; ++c) {
      float4 a = *(const float4*)(qp + c * 32);
      float4 b = *(const float4*)(qp + c * 32 + 4);
      const float s = 0.0078125f;
      a.x *= s; a.y *= s; a.z *= s; a.w *= s;
      b.x *= s; b.y *= s; b.z *= s; b.w *= s;
      qf[c] = pack8(a, b);
    }
  }

  float m_r[4], l_r[4];
  f32x4 o_acc[8];
  #pragma unroll
  for (int r = 0; r < 4; ++r) { m_r[r] = -INFINITY; l_r[r] = 0.f; }
  #pragma unroll
  for (int dt = 0; dt < 8; ++dt) o_acc[dt] = (f32x4){0.f, 0.f, 0.f, 0.f};

  for (int kv0 = 0; kv0 < S_LEN; kv0 += 64) {
    {
      const float* kb = kg + base + (size_t)kv0 * D_DIM;
      #pragma unroll
      for (int c = tid; c < 64 * D_DIM / 8; c += 256) {
        int row = c >> 4, dc = c & 15;
        const float* p = kb + row * D_DIM + dc * 8;
        float4 a = *(const float4*)p;
        float4 b = *(const float4*)(p + 4);
        int sidx = row * 128 + ((dc * 8) ^ ((row & 7) << 3));
        *(short8*)&K_lds[sidx] = pack8(a, b);
      }
    }
    {
      const float* vb = vg + base + (size_t)kv0 * D_DIM;
      #pragma unroll
      for (int u = tid; u < (64 / 4) * (D_DIM / 4); u += 256) {
        int ib = u & 15;
        int db = u >> 4;
        const float* p = vb + (ib * 4) * D_DIM + db * 4;
        float rr[4][4];
        #pragma unroll
        for (int c = 0; c < 4; ++c) {
          float4 t = *(const float4*)(p + c * D_DIM);
          rr[c][0] = t.x; rr[c][1] = t.y; rr[c][2] = t.z; rr[c][3] = t.w;
        }
        #pragma unroll
        for (int j = 0; j < 4; ++j) {
          short4v w;
          w[0] = (short)f2bf(rr[0][j]); w[1] = (short)f2bf(rr[1][j]);
          w[2] = (short)f2bf(rr[2][j]); w[3] = (short)f2bf(rr[3][j]);
          int row = db * 4 + j;
          int sidx = row * 64 + ((ib * 4) ^ ((row & 7) << 3));
          *(short4v*)&VT_lds[sidx] = w;
        }
      }
    }
    __syncthreads();

    f32x4 sacc[4];
    #pragma unroll
    for (int tc = 0; tc < 4; ++tc) sacc[tc] = (f32x4){0.f, 0.f, 0.f, 0.f};
    #pragma unroll
    for (int tc = 0; tc < 4; ++tc) {
      int row = tc * 16 + l15;
      #pragma unroll
      for (int ck = 0; ck < 4; ++ck) {
        int sidx = row * 128 + ((ck * 32 + lg * 8) ^ ((row & 7) << 3));
        short8 kf = *(const short8*)&K_lds[sidx];
        sacc[tc] = __builtin_amdgcn_mfma_f32_16x16x32_bf16(qf[ck], kf, sacc[tc], 0, 0, 0);
      }
    }

    float alpha[4], ps[4];
    #pragma unroll
    for (int r = 0; r < 4; ++r) {
      float a = fmaxf(fmaxf(sacc[0][r], sacc[1][r]), fmaxf(sacc[2][r], sacc[3][r]));
      a = fmaxf(a, __shfl_xor(a, 1));
      a = fmaxf(a, __shfl_xor(a, 2));
      a = fmaxf(a, __shfl_xor(a, 4));
      a = fmaxf(a, __shfl_xor(a, 8));
      float mn = fmaxf(m_r[r], a);
      alpha[r] = __expf(m_r[r] - mn);
      m_r[r] = mn;
      ps[r] = 0.f;
    }
    #pragma unroll
    for (int tc = 0; tc < 4; ++tc) {
      #pragma unroll
      for (int r = 0; r < 4; ++r) {
        float p = __expf(sacc[tc][r] - m_r[r]);
        ps[r] += p;
        int prow = lg * 4 + r;
        int pcol = tc * 16 + l15;
        P_lds[wid][prow * 64 + (pcol ^ ((prow & 7) << 3))] = f2bf(p);
      }
    }
    #pragma unroll
    for (int r = 0; r < 4; ++r) {
      float s = ps[r];
      s += __shfl_xor(s, 1); s += __shfl_xor(s, 2);
      s += __shfl_xor(s, 4); s += __shfl_xor(s, 8);
      l_r[r] = l_r[r] * alpha[r] + s;
    }
    #pragma unroll
    for (int dt = 0; dt < 8; ++dt) {
      #pragma unroll
      for (int r = 0; r < 4; ++r) o_acc[dt][r] *= alpha[r];
    }

    #pragma unroll
    for (int kc = 0; kc < 2; ++kc) {
      int pidx = l15 * 64 + ((kc * 32 + lg * 8) ^ ((l15 & 7) << 3));
      short8 pf = *(const short8*)&P_lds[wid][pidx];
      #pragma unroll
      for (int dt = 0; dt < 8; ++dt) {
        int vrow = dt * 16 + l15;
        int vidx = vrow * 64 + ((kc * 32 + lg * 8) ^ ((vrow & 7) << 3));
        short8 vf = *(const short8*)&VT_lds[vidx];
        o_acc[dt] = __builtin_amdgcn_mfma_f32_16x16x32_bf16(pf, vf, o_acc[dt], 0, 0, 0);
      }
    }
    __syncthreads();
  }

  #pragma unroll
  for (int r = 0; r < 4; ++r) {
    float inv = 1.0f / l_r[r];
    float* op = og + base + (size_t)(qw + lg * 4 + r) * D_DIM + l15;
    #pragma unroll
    for (int dt = 0; dt < 8; ++dt) op[dt * 16] = o_acc[dt][r] * inv;
  }
}

extern "C" void kernel_launch(void* const* d_in, const int* in_sizes, int n_in,
                              void* d_out, int out_size, void* d_ws, size_t ws_size,
                              hipStream_t stream) {
  const float* q = (const float*)d_in[0];
  const float* k = (const float*)d_in[1];
  const float* v = (const float*)d_in[2];
  float* o = (float*)d_out;

  const size_t n_elem = (size_t)BH_N * S_LEN * D_DIM;
  const size_t need = 2 * n_elem * sizeof(unsigned short);

  if (ws_size >= need) {
    unsigned short* kbf = (unsigned short*)d_ws;
    unsigned short* vtbf = kbf + n_elem;
    conv_k<<<dim3(2048), dim3(256), 0, stream>>>(k, kbf, (int)(n_elem / 8));
    conv_vt<<<dim3(4096), dim3(256), 0, stream>>>(v, vtbf);
    attn_main<<<dim3(1024), dim3(256), 0, stream>>>(q, kbf, vtbf, o);
  } else {
    attn_fused<<<dim3(2048), dim3(256), 0, stream>>>(q, k, v, o);
  }
}